// Round 4
// baseline (340.574 us; speedup 1.0000x reference)
//
#include <hip/hip_runtime.h>
#include <math.h>

// Problem constants: B=4, N=4096, D_in=256, D_out=128
#define NTOK 4096
#define RTOT 16384   // B*N
#define DIN  256
#define DOUT 128

constexpr float LEAKY = 0.01f;
constexpr float THR   = 0.1f;

typedef __attribute__((ext_vector_type(8)))  short bf16x8;   // 8 bf16 = 4 VGPRs
typedef __attribute__((ext_vector_type(16))) float f32x16;   // mfma 32x32 acc
typedef __attribute__((ext_vector_type(4)))  float f32x4;    // native vec4 (nt-store ok)

// round-to-nearest-even f32 -> bf16 (bit pattern)
__device__ __forceinline__ unsigned short f2bf(float x) {
    unsigned u = __float_as_uint(x);
    unsigned r = (u + 0x7fffu + ((u >> 16) & 1u)) >> 16;
    return (unsigned short)r;
}
__device__ __forceinline__ float bf2f(unsigned short h) {
    return __uint_as_float((unsigned)h << 16);
}

// async global->LDS, 16B per lane. LDS dest is wave-uniform base + lane*16.
__device__ __forceinline__ void gload_lds16(const void* g, void* l) {
    __builtin_amdgcn_global_load_lds(
        (const __attribute__((address_space(1))) void*)g,
        (__attribute__((address_space(3))) void*)l,
        16, 0, 0);
}

// ---------------------------------------------------------------------------
// Kernel 1: H = leaky_relu(A @ W); row-normalize; emit split-bf16 Hhi/Hlo.
// hn = h / ||h||  (dots of hn ARE cosines; eps branch dead: norms ~ 8)
// Hhi = bf16(hn), Hlo = bf16(hn - Hhi)  -> 3-product GEMM gives ~1e-7 accuracy
// ---------------------------------------------------------------------------
__global__ __launch_bounds__(256, 2) void proj_kernel(
    const float* __restrict__ A, const float* __restrict__ W,
    unsigned short* __restrict__ Hhi, unsigned short* __restrict__ Hlo)
{
    __shared__ float As[32 * DIN];    // 32 KB
    __shared__ float Ws[64 * DOUT];   // 32 KB
    const int tid  = threadIdx.x;
    const int row0 = blockIdx.x * 32;

    {
        const float4* src = (const float4*)(A + (size_t)row0 * DIN);
        float4* dst = (float4*)As;
        #pragma unroll
        for (int it = 0; it < 8; ++it)
            dst[tid + it * 256] = src[tid + it * 256];
    }

    const int tx = tid & 31;
    const int ty = tid >> 5;

    float acc[4][4];
    #pragma unroll
    for (int i = 0; i < 4; ++i)
        #pragma unroll
        for (int j = 0; j < 4; ++j) acc[i][j] = 0.f;

    for (int kc = 0; kc < DIN; kc += 64) {
        __syncthreads();
        {
            const float4* wsrc = (const float4*)(W + (size_t)kc * DOUT);
            float4* wdst = (float4*)Ws;
            #pragma unroll
            for (int it = 0; it < 8; ++it)
                wdst[tid + it * 256] = wsrc[tid + it * 256];
        }
        __syncthreads();

        for (int k = 0; k < 64; k += 4) {
            float4 w4[4];
            #pragma unroll
            for (int s = 0; s < 4; ++s)
                w4[s] = *(const float4*)(Ws + (k + s) * DOUT + 4 * tx);
            #pragma unroll
            for (int i = 0; i < 4; ++i) {
                float4 a4 = *(const float4*)(As + (ty + 8 * i) * DIN + kc + k);
                float ak[4] = {a4.x, a4.y, a4.z, a4.w};
                #pragma unroll
                for (int s = 0; s < 4; ++s) {
                    float wj[4] = {w4[s].x, w4[s].y, w4[s].z, w4[s].w};
                    #pragma unroll
                    for (int j = 0; j < 4; ++j)
                        acc[i][j] = fmaf(ak[s], wj[j], acc[i][j]);
                }
            }
        }
    }

    #pragma unroll
    for (int i = 0; i < 4; ++i) {
        float h[4];
        float s = 0.f;
        #pragma unroll
        for (int j = 0; j < 4; ++j) {
            float v = acc[i][j];
            h[j] = (v >= 0.f) ? v : LEAKY * v;
            s = fmaf(h[j], h[j], s);
        }
        #pragma unroll
        for (int m = 16; m >= 1; m >>= 1)
            s += __shfl_xor(s, m, 64);
        const float rinv = 1.0f / sqrtf(s);
        const int r = row0 + ty + 8 * i;
        ushort4 hv, lv;
        {
            float n0 = h[0] * rinv; hv.x = f2bf(n0); lv.x = f2bf(n0 - bf2f(hv.x));
            float n1 = h[1] * rinv; hv.y = f2bf(n1); lv.y = f2bf(n1 - bf2f(hv.y));
            float n2 = h[2] * rinv; hv.z = f2bf(n2); lv.z = f2bf(n2 - bf2f(hv.z));
            float n3 = h[3] * rinv; hv.w = f2bf(n3); lv.w = f2bf(n3 - bf2f(hv.w));
        }
        *(ushort4*)(Hhi + (size_t)r * DOUT + 4 * tx) = hv;
        *(ushort4*)(Hlo + (size_t)r * DOUT + 4 * tx) = lv;
    }
}

// ---------------------------------------------------------------------------
// Kernel 2: cos tile GEMM on the matrix pipe.
// acc += Ahi*Bhi + Ahi*Blo + Alo*Bhi   (fp32 accum), 128x128 tile per block.
//
// KC=16, double-buffered LDS (2 x 16KB), 2-phase pipeline: STAGE(t+1) issued
// BEFORE ds_read+MFMA of tile t; single __syncthreads per round (its vmcnt(0)
// drain is cheap: loads had the whole MFMA phase in flight).
//
// LDS unit layout per 4KB section (128 rows x 2 k-halves of 16B), chosen so
// ds_read_b128 reads are contiguous 128B per 8-lane group (conflict-free):
//   unit(r,hh) = (r>>3)*16 + hh*8 + (r&7);  byte = unit*16
// global_load_lds dest is linear in (it*64+lane); the global SOURCE address
// applies the inverse mapping (m173): lane l -> row (l>>4)*8+(l&7) (+32/it),
// k-half (l>>3)&1.  Wave w stages section w (0:Ahi 1:Alo 2:Bhi 3:Blo).
//
// Epilogue: transpose acc through LDS (reuse staging, 2 halves of 64 rows) so
// output stores are f32x4 nontemporal, 1KB contiguous per wave-inst.
// ---------------------------------------------------------------------------
__global__ __launch_bounds__(256, 4) void cos_kernel(
    const unsigned short* __restrict__ Hhi,
    const unsigned short* __restrict__ Hlo,
    float* __restrict__ out)
{
    __shared__ __align__(16) char smem[32768];   // 2 x 16KB staging; reused 32KB transpose

    const int b  = blockIdx.y;
    const int ti = (blockIdx.x >> 5) << 7;    // row tile base (token)
    const int tj = (blockIdx.x & 31) << 7;    // col tile base (token)
    const int bN = b * NTOK;

    const int tid  = threadIdx.x;
    const int wave = tid >> 6;
    const int lane = tid & 63;
    const int qr = wave & 1;           // row quadrant (0..1)
    const int qc = wave >> 1;          // col quadrant (0..1)
    const int lr = lane & 31;          // mfma operand row within 32-tile
    const int hh = lane >> 5;          // k-half selector (frag k = 8*hh + e)

    // staging: per-lane pre-swizzled global source (section = wave)
    const unsigned short* gsrc =
        ((wave & 1) ? Hlo : Hhi)
        + (((size_t)(bN + ((wave >> 1) ? tj : ti)
                     + ((lane >> 4) << 3) + (lane & 7))) << 7)
        + (((lane >> 3) & 1) << 3);
    const int lsec = wave << 12;              // 4KB section base within buffer

    // per-lane ds_read byte offsets within a buffer (A uses qr, B uses qc)
    int offA[2], offB[2];
    #pragma unroll
    for (int t = 0; t < 2; ++t) {
        offA[t] = (((qr * 8 + t * 4 + (lr >> 3)) << 8) | (hh << 7) | ((lr & 7) << 4));
        offB[t] = (((qc * 8 + t * 4 + (lr >> 3)) << 8) | (hh << 7) | ((lr & 7) << 4));
    }

    f32x16 acc[2][2];
    #pragma unroll
    for (int i = 0; i < 2; ++i)
        #pragma unroll
        for (int j = 0; j < 2; ++j)
            #pragma unroll
            for (int e = 0; e < 16; ++e)
                acc[i][j][e] = 0.f;

    // prologue: stage round 0 into buf0
    #pragma unroll
    for (int it = 0; it < 4; ++it)
        gload_lds16(gsrc + it * 32 * DOUT, smem + lsec + (it << 10));
    __syncthreads();

    int cur = 0;
    #pragma unroll
    for (int r = 0; r < 8; ++r) {
        // issue next-round staging first (overlaps with compute below)
        if (r < 7) {
            const unsigned short* g = gsrc + (r + 1) * 16;
            char* l = smem + ((cur ^ 1) << 14) + lsec;
            #pragma unroll
            for (int it = 0; it < 4; ++it)
                gload_lds16(g + it * 32 * DOUT, l + (it << 10));
        }

        const char* base = smem + (cur << 14);
        bf16x8 ah[2], al[2], bh[2], bl[2];
        #pragma unroll
        for (int t = 0; t < 2; ++t) {
            ah[t] = *(const bf16x8*)(base +         offA[t]);
            al[t] = *(const bf16x8*)(base +  4096 + offA[t]);
            bh[t] = *(const bf16x8*)(base +  8192 + offB[t]);
            bl[t] = *(const bf16x8*)(base + 12288 + offB[t]);
        }
        #pragma unroll
        for (int i = 0; i < 2; ++i)
            #pragma unroll
            for (int j = 0; j < 2; ++j) {
                acc[i][j] = __builtin_amdgcn_mfma_f32_32x32x16_bf16(
                                ah[i], bh[j], acc[i][j], 0, 0, 0);
                acc[i][j] = __builtin_amdgcn_mfma_f32_32x32x16_bf16(
                                ah[i], bl[j], acc[i][j], 0, 0, 0);
                acc[i][j] = __builtin_amdgcn_mfma_f32_32x32x16_bf16(
                                al[i], bh[j], acc[i][j], 0, 0, 0);
            }
        __syncthreads();   // drains vmcnt(0) (next stage landed) + lgkm
        cur ^= 1;
    }

    // Epilogue: abs+threshold, transpose through LDS, f32x4 nt stores.
    // C/D layout (32x32x16): col = lane&31, row = (v&3) + 8*(v>>2) + 4*hh
    float* Ob = out + (size_t)b * NTOK * NTOK;
    float* T = (float*)smem;                   // [64][128] per half
    #pragma unroll
    for (int h = 0; h < 2; ++h) {
        if (qr == h) {
            #pragma unroll
            for (int i = 0; i < 2; ++i)
                #pragma unroll
                for (int j = 0; j < 2; ++j) {
                    const int c0 = qc * 64 + j * 32 + lr;
                    #pragma unroll
                    for (int v = 0; v < 16; ++v) {
                        const int rt = i * 32 + (hh << 2) + (v & 3) + ((v >> 2) << 3);
                        float x = fabsf(acc[i][j][v]);
                        x = (x > THR) ? x : 0.f;
                        T[(rt << 7) + c0] = x;
                    }
                }
        }
        __syncthreads();
        #pragma unroll
        for (int it = 0; it < 8; ++it) {
            const int idx = tid + it * 256;
            const int rt  = idx >> 5;          // 0..63
            const int c   = (idx & 31) << 2;   // 0..124
            f32x4 v = *(const f32x4*)(T + (rt << 7) + c);
            __builtin_nontemporal_store(
                v, (f32x4*)(Ob + (size_t)(ti + h * 64 + rt) * NTOK + tj + c));
        }
        __syncthreads();
    }
}

extern "C" void kernel_launch(void* const* d_in, const int* in_sizes, int n_in,
                              void* d_out, int out_size, void* d_ws, size_t ws_size,
                              hipStream_t stream) {
    const float* A = (const float*)d_in[0];   // [4,4096,256]
    const float* W = (const float*)d_in[1];   // [256,128]
    float* out = (float*)d_out;               // [4,4096,4096]

    unsigned short* Hhi = (unsigned short*)d_ws;            // 4 MB
    unsigned short* Hlo = Hhi + (size_t)RTOT * DOUT;        // 4 MB

    proj_kernel<<<RTOT / 32, 256, 0, stream>>>(A, W, Hhi, Hlo);
    cos_kernel<<<dim3(1024, 4), 256, 0, stream>>>(Hhi, Hlo, out);
}

// Round 5
// 327.898 us; speedup vs baseline: 1.0387x; 1.0387x over previous
//
#include <hip/hip_runtime.h>
#include <math.h>

// Problem constants: B=4, N=4096, D_in=256, D_out=128
#define NTOK 4096
#define RTOT 16384   // B*N
#define DIN  256
#define DOUT 128

constexpr float LEAKY = 0.01f;
constexpr float THR   = 0.1f;

typedef __attribute__((ext_vector_type(8)))  short bf16x8;   // 8 bf16 = 4 VGPRs
typedef __attribute__((ext_vector_type(16))) float f32x16;   // mfma 32x32 acc

// round-to-nearest-even f32 -> bf16 (bit pattern)
__device__ __forceinline__ unsigned short f2bf(float x) {
    unsigned u = __float_as_uint(x);
    unsigned r = (u + 0x7fffu + ((u >> 16) & 1u)) >> 16;
    return (unsigned short)r;
}
__device__ __forceinline__ float bf2f(unsigned short h) {
    return __uint_as_float((unsigned)h << 16);
}

// async global->LDS, 16B per lane. LDS dest is wave-uniform base + lane*16.
__device__ __forceinline__ void gload_lds16(const void* g, void* l) {
    __builtin_amdgcn_global_load_lds(
        (const __attribute__((address_space(1))) void*)g,
        (__attribute__((address_space(3))) void*)l,
        16, 0, 0);
}

// ---------------------------------------------------------------------------
// Kernel 1: H = leaky_relu(A @ W); row-normalize; emit split-bf16 Hhi/Hlo.
// hn = h / ||h||  (dots of hn ARE cosines; eps branch dead: norms ~ 8)
// Hhi = bf16(hn), Hlo = bf16(hn - Hhi)  -> 3-product GEMM gives ~1e-7 accuracy
// ---------------------------------------------------------------------------
__global__ __launch_bounds__(256, 2) void proj_kernel(
    const float* __restrict__ A, const float* __restrict__ W,
    unsigned short* __restrict__ Hhi, unsigned short* __restrict__ Hlo)
{
    __shared__ float As[32 * DIN];    // 32 KB
    __shared__ float Ws[64 * DOUT];   // 32 KB
    const int tid  = threadIdx.x;
    const int row0 = blockIdx.x * 32;

    {
        const float4* src = (const float4*)(A + (size_t)row0 * DIN);
        float4* dst = (float4*)As;
        #pragma unroll
        for (int it = 0; it < 8; ++it)
            dst[tid + it * 256] = src[tid + it * 256];
    }

    const int tx = tid & 31;
    const int ty = tid >> 5;

    float acc[4][4];
    #pragma unroll
    for (int i = 0; i < 4; ++i)
        #pragma unroll
        for (int j = 0; j < 4; ++j) acc[i][j] = 0.f;

    for (int kc = 0; kc < DIN; kc += 64) {
        __syncthreads();
        {
            const float4* wsrc = (const float4*)(W + (size_t)kc * DOUT);
            float4* wdst = (float4*)Ws;
            #pragma unroll
            for (int it = 0; it < 8; ++it)
                wdst[tid + it * 256] = wsrc[tid + it * 256];
        }
        __syncthreads();

        for (int k = 0; k < 64; k += 4) {
            float4 w4[4];
            #pragma unroll
            for (int s = 0; s < 4; ++s)
                w4[s] = *(const float4*)(Ws + (k + s) * DOUT + 4 * tx);
            #pragma unroll
            for (int i = 0; i < 4; ++i) {
                float4 a4 = *(const float4*)(As + (ty + 8 * i) * DIN + kc + k);
                float ak[4] = {a4.x, a4.y, a4.z, a4.w};
                #pragma unroll
                for (int s = 0; s < 4; ++s) {
                    float wj[4] = {w4[s].x, w4[s].y, w4[s].z, w4[s].w};
                    #pragma unroll
                    for (int j = 0; j < 4; ++j)
                        acc[i][j] = fmaf(ak[s], wj[j], acc[i][j]);
                }
            }
        }
    }

    #pragma unroll
    for (int i = 0; i < 4; ++i) {
        float h[4];
        float s = 0.f;
        #pragma unroll
        for (int j = 0; j < 4; ++j) {
            float v = acc[i][j];
            h[j] = (v >= 0.f) ? v : LEAKY * v;
            s = fmaf(h[j], h[j], s);
        }
        #pragma unroll
        for (int m = 16; m >= 1; m >>= 1)
            s += __shfl_xor(s, m, 64);
        const float rinv = 1.0f / sqrtf(s);
        const int r = row0 + ty + 8 * i;
        ushort4 hv, lv;
        {
            float n0 = h[0] * rinv; hv.x = f2bf(n0); lv.x = f2bf(n0 - bf2f(hv.x));
            float n1 = h[1] * rinv; hv.y = f2bf(n1); lv.y = f2bf(n1 - bf2f(hv.y));
            float n2 = h[2] * rinv; hv.z = f2bf(n2); lv.z = f2bf(n2 - bf2f(hv.z));
            float n3 = h[3] * rinv; hv.w = f2bf(n3); lv.w = f2bf(n3 - bf2f(hv.w));
        }
        *(ushort4*)(Hhi + (size_t)r * DOUT + 4 * tx) = hv;
        *(ushort4*)(Hlo + (size_t)r * DOUT + 4 * tx) = lv;
    }
}

// ---------------------------------------------------------------------------
// Kernel 2: cos tile GEMM on the matrix pipe (R2 structure + XCD L2 pinning).
// acc += Ahi*Bhi + Ahi*Blo + Alo*Bhi   (fp32 accum), 128x128 tile per block.
//
// XCD L2 pinning: per batch, H_b (hi+lo) = 2 MB fits one XCD's 4 MB L2.
// 1D grid of 4096; measured dispatch mapping is xcd = bid & 7.  XCD pair
// {b, b+4} owns batch b = xcd & 3, splitting its 32x32 tile grid in half:
//   slot = bid >> 3 (0..511), tile = (xcd>>2)*512 + slot.
// Every panel read after warm-up hits the XCD-private L2 instead of L3/HBM
// (R0 evidence: 114 MB HBM fetch for 8 MB of unique input = L3 thrash).
// nt output stores keep the 268 MB stream from evicting the pinned panels.
//
// Staging uses global_load_lds width=16; LDS dest linear per-lane (m104),
// slot-XOR swizzle applied to the per-lane GLOBAL source address (m173).
// Wave w stages section w (0:Ahi 1:Alo 2:Bhi 3:Blo, 8KB each).
// ---------------------------------------------------------------------------
__global__ __launch_bounds__(256, 4) void cos_kernel(
    const unsigned short* __restrict__ Hhi,
    const unsigned short* __restrict__ Hlo,
    float* __restrict__ out)
{
    __shared__ uint4 smem4[2048];        // 32 KB: [Ahi|Alo|Bhi|Blo], 8KB each
    char* smem = (char*)smem4;

    const int bid  = blockIdx.x;
    const int xcd  = bid & 7;
    const int slot = bid >> 3;
    const int b    = xcd & 3;                      // batch pinned to XCD pair
    const int tile = ((xcd >> 2) << 9) + slot;     // 0..1023
    const int ti = (tile >> 5) << 7;               // row tile base (token)
    const int tj = (tile & 31) << 7;               // col tile base (token)
    const int bN = b * NTOK;

    const int tid  = threadIdx.x;
    const int wave = tid >> 6;
    const int lane = tid & 63;
    const int qr = wave & 1;           // row quadrant (0..1)
    const int qc = wave >> 1;          // col quadrant (0..1)
    const int lr = lane & 31;          // mfma operand row within 32-tile
    const int hh = lane >> 5;          // k-slot half selector

    // per-lane staging source (elements); section chosen by wave
    const unsigned short* gbase =
        ((wave & 1) ? Hlo : Hhi)
        + (((size_t)(bN + ((wave >> 1) ? tj : ti) + (lane >> 2))) << 7)
        + ((size_t)(((lane & 3) ^ ((lane >> 2) & 3)) << 3));
    char* lbase = smem + (wave << 13);   // wave-uniform section base

    f32x16 acc[2][2];
    #pragma unroll
    for (int i = 0; i < 2; ++i)
        #pragma unroll
        for (int j = 0; j < 2; ++j)
            #pragma unroll
            for (int e = 0; e < 16; ++e)
                acc[i][j][e] = 0.f;

    for (int kc = 0; kc < DOUT; kc += 32) {
        __syncthreads();
        #pragma unroll
        for (int it = 0; it < 8; ++it)
            gload_lds16(gbase + kc + it * 2048, lbase + (it << 10));
        __syncthreads();   // compiler emits vmcnt(0) drain before s_barrier

        #pragma unroll
        for (int ks = 0; ks < 2; ++ks) {
            bf16x8 ah[2], al[2], bh[2], bl[2];
            const int s = (ks << 1) | hh;     // frag slot: k = kc + 8*s .. +8
            #pragma unroll
            for (int t = 0; t < 2; ++t) {
                const int ra = qr * 64 + t * 32 + lr;
                const int oa = (ra << 6) + ((s ^ (ra & 3)) << 4);
                ah[t] = *(const bf16x8*)(smem + oa);
                al[t] = *(const bf16x8*)(smem + 8192 + oa);
                const int rb = qc * 64 + t * 32 + lr;
                const int ob = (rb << 6) + ((s ^ (rb & 3)) << 4);
                bh[t] = *(const bf16x8*)(smem + 16384 + ob);
                bl[t] = *(const bf16x8*)(smem + 24576 + ob);
            }
            #pragma unroll
            for (int i = 0; i < 2; ++i)
                #pragma unroll
                for (int j = 0; j < 2; ++j) {
                    acc[i][j] = __builtin_amdgcn_mfma_f32_32x32x16_bf16(
                                    ah[i], bh[j], acc[i][j], 0, 0, 0);
                    acc[i][j] = __builtin_amdgcn_mfma_f32_32x32x16_bf16(
                                    ah[i], bl[j], acc[i][j], 0, 0, 0);
                    acc[i][j] = __builtin_amdgcn_mfma_f32_32x32x16_bf16(
                                    al[i], bh[j], acc[i][j], 0, 0, 0);
                }
        }
    }

    // Epilogue: abs + threshold, nontemporal coalesced stores.
    // C/D layout (32x32x16): col = lane&31, row = (v&3) + 8*(v>>2) + 4*(lane>>5)
    float* Ob = out + (size_t)b * NTOK * NTOK;
    const int col = tj + qc * 64 + lr;
    #pragma unroll
    for (int i = 0; i < 2; ++i) {
        const int rbase = ti + qr * 64 + i * 32 + (hh << 2);
        #pragma unroll
        for (int j = 0; j < 2; ++j) {
            const int c = col + j * 32;
            #pragma unroll
            for (int v = 0; v < 16; ++v) {
                const int row = rbase + (v & 3) + ((v >> 2) << 3);
                float x = fabsf(acc[i][j][v]);
                x = (x > THR) ? x : 0.f;
                __builtin_nontemporal_store(x, Ob + (size_t)row * NTOK + c);
            }
        }
    }
}

extern "C" void kernel_launch(void* const* d_in, const int* in_sizes, int n_in,
                              void* d_out, int out_size, void* d_ws, size_t ws_size,
                              hipStream_t stream) {
    const float* A = (const float*)d_in[0];   // [4,4096,256]
    const float* W = (const float*)d_in[1];   // [256,128]
    float* out = (float*)d_out;               // [4,4096,4096]

    unsigned short* Hhi = (unsigned short*)d_ws;            // 4 MB
    unsigned short* Hlo = Hhi + (size_t)RTOT * DOUT;        // 4 MB

    proj_kernel<<<RTOT / 32, 256, 0, stream>>>(A, W, Hhi, Hlo);
    cos_kernel<<<4096, 256, 0, stream>>>(Hhi, Hlo, out);
}